// Round 19
// baseline (228.223 us; speedup 1.0000x reference)
//
#include <hip/hip_runtime.h>

#define L_SEQ   2048
#define D_MODEL 1024
#define N_QKV   3072

typedef __attribute__((ext_vector_type(8)))  short short8;
typedef __attribute__((ext_vector_type(4)))  float f32x4;
typedef __attribute__((ext_vector_type(16))) float f32x16;

__device__ __forceinline__ unsigned short f2bf(float f){
    unsigned int u = __float_as_uint(f);
    u += 0x7fffu + ((u >> 16) & 1u);
    return (unsigned short)(u >> 16);
}

__device__ __forceinline__ void gload16(const void* g, void* l){
    __builtin_amdgcn_global_load_lds(
        (const __attribute__((address_space(1))) unsigned int*)g,
        (__attribute__((address_space(3))) unsigned int*)l, 16, 0, 0);
}

__device__ __forceinline__ unsigned int cvtpk_bf16(float lo, float hi){
    unsigned int r;
    asm volatile("v_cvt_pk_bf16_f32 %0, %1, %2" : "=v"(r) : "v"(lo), "v"(hi));
    return r;
}

// ---------------- RoPE cos/sin table ----------------
__global__ void rope_table_kernel(float* __restrict__ cost, float* __restrict__ sint){
    int idx = blockIdx.x * blockDim.x + threadIdx.x;   // l*32 + i
    if (idx >= L_SEQ * 32) return;
    int l = idx >> 5;
    int i = idx & 31;
    double e = (double)(2 * i) / 64.0;
    float invf = (float)pow(10000.0, -e);
    float f = (float)l * invf;
    cost[idx] = cosf(f);
    sint[idx] = sinf(f);
}

// ---------------- fp32 -> bf16 elementwise ----------------
__global__ __launch_bounds__(256) void cvt_bf16_kernel(
    const float* __restrict__ in, unsigned short* __restrict__ out)
{
    int i = (blockIdx.x * 256 + threadIdx.x) * 4;
    float4 v = *(const float4*)(in + i);
    ushort4 o;
    o.x = f2bf(v.x); o.y = f2bf(v.y); o.z = f2bf(v.z); o.w = f2bf(v.w);
    *(ushort4*)(out + i) = o;
}

// ---------------- transpose + convert: W[K][N] fp32 -> WT[N][K] bf16 ----------------
__global__ __launch_bounds__(256) void transpose_bf16_kernel(
    const float* __restrict__ W, unsigned short* __restrict__ WT, int K, int N)
{
    __shared__ float T[64][65];
    const int k0 = blockIdx.y * 64, n0 = blockIdx.x * 64;
    const int r  = threadIdx.x >> 4;
    const int c4 = (threadIdx.x & 15) * 4;
    #pragma unroll
    for (int i = 0; i < 4; ++i){
        int row = r + i * 16;
        float4 v = *(const float4*)&W[(size_t)(k0 + row) * N + n0 + c4];
        T[row][c4 + 0] = v.x; T[row][c4 + 1] = v.y;
        T[row][c4 + 2] = v.z; T[row][c4 + 3] = v.w;
    }
    __syncthreads();
    #pragma unroll
    for (int i = 0; i < 4; ++i){
        int nl = r + i * 16;
        ushort4 o;
        o.x = f2bf(T[c4 + 0][nl]); o.y = f2bf(T[c4 + 1][nl]);
        o.z = f2bf(T[c4 + 2][nl]); o.w = f2bf(T[c4 + 3][nl]);
        *(ushort4*)&WT[(size_t)(n0 + nl) * K + k0 + c4] = o;
    }
}

// ---------------- QKV MFMA GEMM (8192x3072x1024) + RoPE + LDS-staged stores ----------
// 512 threads / 8 waves per 128x128 tile; BK=64 single-buffer 2-barrier loop.
// q -> [bh][l][d] (scaled by exactly 0.125); k -> [bh][key][d]; v -> [bh][d][key]
__global__ __launch_bounds__(512, 4) void qkv_mfma_kernel(
    const unsigned short* __restrict__ A, const unsigned short* __restrict__ BT,
    const float* __restrict__ cost, const float* __restrict__ sint,
    unsigned short* __restrict__ qb, unsigned short* __restrict__ kb,
    unsigned short* __restrict__ vtb)
{
    __shared__ __align__(16) unsigned char smem[34816];   // Al(16K)+Bl(16K) / T 128x136
    unsigned short* Al = (unsigned short*)smem;
    unsigned short* Bl = Al + 8192;
    unsigned short* T  = (unsigned short*)smem;           // [128][136] after K-loop

    const int tid  = threadIdx.x;
    const int lane = tid & 63;
    const int w    = tid >> 6;          // 0..7
    const int wm   = w & 1, wn = w >> 1;   // m-half, n-quarter
    const int l15  = lane & 15, l4 = lane >> 4;
    const int m0   = blockIdx.y * 128;
    const int n0   = blockIdx.x * 128;

    const int srow = tid >> 3;          // 0..63
    const int scol = ((tid & 7) * 8) ^ ((srow & 7) * 8);   // T2 pre-swizzled source
    const int ksw  = (l15 & 7) * 8;                        // read-side XOR key

    f32x4 acc[4][2];
    #pragma unroll
    for (int i = 0; i < 4; ++i)
        #pragma unroll
        for (int j = 0; j < 2; ++j)
            acc[i][j] = (f32x4){0.f, 0.f, 0.f, 0.f};

    for (int k0 = 0; k0 < 1024; k0 += 64){
        #pragma unroll
        for (int c = 0; c < 2; ++c){
            gload16(&A [(size_t)(m0 + c * 64 + srow) * 1024 + k0 + scol],
                    &Al[c * 4096 + w * 512]);
            gload16(&BT[(size_t)(n0 + c * 64 + srow) * 1024 + k0 + scol],
                    &Bl[c * 4096 + w * 512]);
        }
        __syncthreads();
        #pragma unroll
        for (int kc = 0; kc < 2; ++kc){
            short8 a[4], b[2];
            #pragma unroll
            for (int mi = 0; mi < 4; ++mi)
                a[mi] = *(const short8*)&Al[(wm * 64 + mi * 16 + l15) * 64 + ((kc * 32 + l4 * 8) ^ ksw)];
            #pragma unroll
            for (int ni = 0; ni < 2; ++ni)
                b[ni] = *(const short8*)&Bl[(wn * 32 + ni * 16 + l15) * 64 + ((kc * 32 + l4 * 8) ^ ksw)];
            #pragma unroll
            for (int mi = 0; mi < 4; ++mi)
                #pragma unroll
                for (int ni = 0; ni < 2; ++ni)
                    acc[mi][ni] = __builtin_amdgcn_mfma_f32_16x16x32_bf16(a[mi], b[ni], acc[mi][ni], 0, 0, 0);
        }
        __syncthreads();
    }

    // ---- epilogue: RoPE in registers -> LDS tile -> coalesced 16B stores ----
    const int which = n0 >> 10;           // block-uniform: 0=q 1=k 2=v
    #pragma unroll
    for (int ni = 0; ni < 2; ++ni){
        const int c  = wn * 32 + ni * 16 + l15;       // block-local col
        const int d  = (n0 + c) & 63;
        const int fi = d >> 1;
        const float sgn = (d & 1) ? 1.0f : -1.0f;
        #pragma unroll
        for (int mi = 0; mi < 4; ++mi){
            const int row0 = wm * 64 + mi * 16 + l4 * 4;
            if (which == 2){
                ushort4 pk;
                pk.x = f2bf(acc[mi][ni][0]); pk.y = f2bf(acc[mi][ni][1]);
                pk.z = f2bf(acc[mi][ni][2]); pk.w = f2bf(acc[mi][ni][3]);
                *(ushort4*)&T[c * 136 + row0] = pk;            // transposed [c][l]
            } else {
                #pragma unroll
                for (int r = 0; r < 4; ++r){
                    int row = row0 + r;
                    int gl  = (m0 + row) & 2047;
                    float val = acc[mi][ni][r];
                    float cs = cost[gl * 32 + fi];
                    float sn = sint[gl * 32 + fi];
                    float partner = __shfl_xor(val, 1);
                    float outv = val * cs + sgn * partner * sn;
                    // q scaled by exactly 1/8 (bf16-exact); softmax runs base-e
                    if (which == 0) outv *= 0.125f;
                    T[row * 136 + c] = f2bf(outv);             // natural [l][c]
                }
            }
        }
    }
    __syncthreads();

    const int bidx = m0 >> 11;
    if (which == 2){
        #pragma unroll
        for (int it = 0; it < 4; ++it){
            int chunk = it * 512 + tid;       // 128 c-rows x 16 l-chunks
            int crow  = chunk >> 4;
            int lch   = chunk & 15;
            short8 v = *(const short8*)&T[crow * 136 + lch * 8];
            int colg = n0 + crow;
            int hh   = (colg & 1023) >> 6;
            int d    = colg & 63;
            int l0   = (m0 & 2047) + lch * 8;
            *(short8*)&vtb[(((size_t)(bidx * 16 + hh)) * 64 + d) * 2048 + l0] = v;
        }
    } else {
        unsigned short* dstb = (which == 0) ? qb : kb;
        #pragma unroll
        for (int it = 0; it < 4; ++it){
            int chunk = it * 512 + tid;       // 128 l-rows x 16 d-chunks
            int row   = chunk >> 4;
            int ch    = chunk & 15;
            short8 v = *(const short8*)&T[row * 136 + ch * 8];
            int gl   = (m0 & 2047) + row;
            int colg = n0 + ch * 8;
            int hh   = (colg & 1023) >> 6;
            int d0   = colg & 63;
            *(short8*)&dstb[(((size_t)(bidx * 16 + hh)) * 2048 + gl) * 64 + d0] = v;
        }
    }
}

// ---------------- proj MFMA GEMM (8192x1024x1024), fp32 out ----------------
__global__ __launch_bounds__(256, 3) void proj_mfma_kernel(
    const unsigned short* __restrict__ A, const unsigned short* __restrict__ BT,
    float* __restrict__ C)
{
    __shared__ __align__(16) unsigned short Al[128 * 64];
    __shared__ __align__(16) unsigned short Bl[128 * 64];

    const int tid  = threadIdx.x;
    const int lane = tid & 63;
    const int w    = tid >> 6;
    const int wm   = w & 1, wn = w >> 1;
    const int l15  = lane & 15, l4 = lane >> 4;
    const int m0   = blockIdx.y * 128;
    const int n0   = blockIdx.x * 128;

    const int srow = tid >> 3;
    const int scol = ((tid & 7) * 8) ^ ((srow & 7) * 8);
    const int ksw  = (l15 & 7) * 8;

    f32x4 acc[4][4];
    #pragma unroll
    for (int i = 0; i < 4; ++i)
        #pragma unroll
        for (int j = 0; j < 4; ++j)
            acc[i][j] = (f32x4){0.f, 0.f, 0.f, 0.f};

    for (int k0 = 0; k0 < 1024; k0 += 64){
        #pragma unroll
        for (int c = 0; c < 4; ++c){
            gload16(&A [(size_t)(m0 + c * 32 + srow) * 1024 + k0 + scol],
                    &Al[c * 2048 + w * 512]);
            gload16(&BT[(size_t)(n0 + c * 32 + srow) * 1024 + k0 + scol],
                    &Bl[c * 2048 + w * 512]);
        }
        __syncthreads();
        #pragma unroll
        for (int kc = 0; kc < 2; ++kc){
            short8 a[4], b[4];
            #pragma unroll
            for (int mi = 0; mi < 4; ++mi)
                a[mi] = *(const short8*)&Al[(wm * 64 + mi * 16 + l15) * 64 + ((kc * 32 + l4 * 8) ^ ksw)];
            #pragma unroll
            for (int ni = 0; ni < 4; ++ni)
                b[ni] = *(const short8*)&Bl[(wn * 64 + ni * 16 + l15) * 64 + ((kc * 32 + l4 * 8) ^ ksw)];
            #pragma unroll
            for (int mi = 0; mi < 4; ++mi)
                #pragma unroll
                for (int ni = 0; ni < 4; ++ni)
                    acc[mi][ni] = __builtin_amdgcn_mfma_f32_16x16x32_bf16(a[mi], b[ni], acc[mi][ni], 0, 0, 0);
        }
        __syncthreads();
    }

    #pragma unroll
    for (int mi = 0; mi < 4; ++mi)
        #pragma unroll
        for (int r = 0; r < 4; ++r){
            int row = m0 + wm * 64 + mi * 16 + l4 * 4 + r;
            #pragma unroll
            for (int ni = 0; ni < 4; ++ni){
                int colc = n0 + wn * 64 + ni * 16 + l15;
                C[(size_t)row * 1024 + colc] = acc[mi][ni][r];
            }
        }
}

// ---------------- swapped-operand 32x32 MFMA flash attention ----------------
// KVBLK=128 (16 tiles, 16 barriers), double-buffered 2x32KB LDS; 8 waves x 32 q.
// Per tile: two 64-key sub-bodies (QK interleaved 2-way, exp, pack, PV).
// Region layout (1KB each): K[sub*8 + grp*4 + kbd], Vt[sub*8 + dblk*4 + kbv].
__global__ __launch_bounds__(512, 4) void attn_mfma32_kernel(
    const unsigned short* __restrict__ qb,   // [bh][l][d] (pre-scaled by 1/8)
    const unsigned short* __restrict__ kb,   // [bh][key][d]
    const unsigned short* __restrict__ vtb,  // [bh][d][key]
    unsigned short* __restrict__ ctx)        // [b*2048+l][1024] bf16
{
    __shared__ __align__(16) unsigned char lds[65536];  // 2 x (K 16KB + Vt 16KB)

    const int tid  = threadIdx.x;
    const int lane = tid & 63;
    const int w    = tid >> 6;          // 0..7
    const int l31  = lane & 31;
    const int hi   = lane >> 5;
    const int blk = blockIdx.x;                 // 0..511
    const int swz = ((blk & 7) << 6) | (blk >> 3);
    const int bh  = swz >> 3;                   // 0..63
    const int qt  = swz & 7;                    // 0..7
    const int b   = bh >> 4, h = bh & 15;

    const unsigned short* Kg  = kb  + (size_t)bh * 2048 * 64;
    const unsigned short* VTg = vtb + (size_t)bh * 64 * 2048;
    const int q0 = qt * 256 + w * 32;
    const unsigned short* Qg = qb + ((size_t)bh * 2048 + q0) * 64;

    short8 qf[4];
    #pragma unroll
    for (int kbd = 0; kbd < 4; ++kbd)
        qf[kbd] = *(const short8*)(Qg + l31 * 64 + hi * 8 + kbd * 16);

    f32x16 o0, o1;
    f32x4  lsv = (f32x4){0.f, 0.f, 0.f, 0.f};
    #pragma unroll
    for (int r = 0; r < 16; ++r){ o0[r] = 0.f; o1[r] = 0.f; }

    // wave w stages K regions {2w, 2w+1} and V regions {2w, 2w+1}
    const int r0i = 2 * w, r1i = 2 * w + 1;
    // K region r: key=(r>>2)*32 + l31 (within 128-key tile), d = hi*8 + (r&3)*16
    const unsigned short* ksrc0 = Kg + ((size_t)((r0i >> 2) * 32 + l31)) * 64 + hi * 8 + (r0i & 3) * 16;
    const unsigned short* ksrc1 = Kg + ((size_t)((r1i >> 2) * 32 + l31)) * 64 + hi * 8 + (r1i & 3) * 16;
    // V region r: d = ((r>>2)&1)*32 + l31, keycol = (r>>3)*64 + (r&3)*16 + hi*8
    const unsigned short* vsrc0 = VTg + ((size_t)(((r0i >> 2) & 1) * 32 + l31)) * 2048 + (r0i >> 3) * 64 + (r0i & 3) * 16 + hi * 8;
    const unsigned short* vsrc1 = VTg + ((size_t)(((r1i >> 2) & 1) * 32 + l31)) * 2048 + (r1i >> 3) * 64 + (r1i & 3) * 16 + hi * 8;

    auto STAGE = [&](int t, int buf){
        unsigned char* base = lds + buf * 32768;
        gload16(ksrc0 + (size_t)t * 8192, base + r0i * 1024);
        gload16(ksrc1 + (size_t)t * 8192, base + r1i * 1024);
        gload16(vsrc0 + (size_t)t * 128, base + 16384 + r0i * 1024);
        gload16(vsrc1 + (size_t)t * 128, base + 16384 + r1i * 1024);
    };

    STAGE(0, 0);

    for (int t = 0; t < 16; ++t){
        // tile t's loads were issued a full tile-compute ago -> cheap drain
        asm volatile("s_waitcnt vmcnt(0)" ::: "memory");
        __builtin_amdgcn_s_barrier();
        if (t < 15) STAGE(t + 1, (t & 1) ^ 1);

        unsigned char* Kl = lds + (t & 1) * 32768;
        unsigned char* Vl = Kl + 16384;

        #pragma unroll
        for (int s = 0; s < 2; ++s){
            // ---- QK^T: two key-groups interleaved (independent accumulators) ----
            f32x16 s0, s1;
            #pragma unroll
            for (int r = 0; r < 16; ++r){ s0[r] = -16.0f; s1[r] = -16.0f; }
            __builtin_amdgcn_s_setprio(1);
            #pragma unroll
            for (int kbd = 0; kbd < 4; ++kbd){
                short8 kfA = *(const short8*)(Kl + (s * 8 + 0 * 4 + kbd) * 1024 + lane * 16);
                short8 kfB = *(const short8*)(Kl + (s * 8 + 1 * 4 + kbd) * 1024 + lane * 16);
                s0 = __builtin_amdgcn_mfma_f32_32x32x16_bf16(kfA, qf[kbd], s0, 0, 0, 0);
                s1 = __builtin_amdgcn_mfma_f32_32x32x16_bf16(kfB, qf[kbd], s1, 0, 0, 0);
            }
            __builtin_amdgcn_s_setprio(0);

            // ---- p = exp(s - 16) via __expf; denominator accumulate ----
            #pragma unroll
            for (int r = 0; r < 16; ++r){
                float p0 = __expf(s0[r]);
                float p1 = __expf(s1[r]);
                s0[r] = p0; s1[r] = p1;
                lsv[r & 3] += p0 + p1;
            }

            // ---- pack to bf16 fragments via cvt_pk + permlane32_swap ----
            short8 pa[4];
            #pragma unroll
            for (int half = 0; half < 2; ++half){
                unsigned int w01 = cvtpk_bf16(s0[half*8+0], s0[half*8+1]);
                unsigned int w23 = cvtpk_bf16(s0[half*8+2], s0[half*8+3]);
                unsigned int w45 = cvtpk_bf16(s0[half*8+4], s0[half*8+5]);
                unsigned int w67 = cvtpk_bf16(s0[half*8+6], s0[half*8+7]);
                asm volatile("v_permlane32_swap_b32 %0, %1" : "+v"(w01), "+v"(w45));
                asm volatile("v_permlane32_swap_b32 %0, %1" : "+v"(w23), "+v"(w67));
                short8 pp;
                pp[0] = (short)(w01 & 0xffffu); pp[1] = (short)(w01 >> 16);
                pp[2] = (short)(w23 & 0xffffu); pp[3] = (short)(w23 >> 16);
                pp[4] = (short)(w45 & 0xffffu); pp[5] = (short)(w45 >> 16);
                pp[6] = (short)(w67 & 0xffffu); pp[7] = (short)(w67 >> 16);
                pa[half] = pp;
            }
            #pragma unroll
            for (int half = 0; half < 2; ++half){
                unsigned int w01 = cvtpk_bf16(s1[half*8+0], s1[half*8+1]);
                unsigned int w23 = cvtpk_bf16(s1[half*8+2], s1[half*8+3]);
                unsigned int w45 = cvtpk_bf16(s1[half*8+4], s1[half*8+5]);
                unsigned int w67 = cvtpk_bf16(s1[half*8+6], s1[half*8+7]);
                asm volatile("v_permlane32_swap_b32 %0, %1" : "+v"(w01), "+v"(w45));
                asm volatile("v_permlane32_swap_b32 %0, %1" : "+v"(w23), "+v"(w67));
                short8 pp;
                pp[0] = (short)(w01 & 0xffffu); pp[1] = (short)(w01 >> 16);
                pp[2] = (short)(w23 & 0xffffu); pp[3] = (short)(w23 >> 16);
                pp[4] = (short)(w45 & 0xffffu); pp[5] = (short)(w45 >> 16);
                pp[6] = (short)(w67 & 0xffffu); pp[7] = (short)(w67 >> 16);
                pa[2 + half] = pp;
            }

            // ---- O^T += V^T . P (o0/o1 alternate: 2-way ILP) ----
            #pragma unroll
            for (int kbv = 0; kbv < 4; ++kbv){
                short8 vf0 = *(const short8*)(Vl + (s * 8 + 0 * 4 + kbv) * 1024 + lane * 16);
                short8 vf1 = *(const short8*)(Vl + (s * 8 + 1 * 4 + kbv) * 1024 + lane * 16);
                __builtin_amdgcn_s_setprio(1);
                o0 = __builtin_amdgcn_mfma_f32_32x32x16_bf16(vf0, pa[kbv], o0, 0, 0, 0);
                o1 = __builtin_amdgcn_mfma_f32_32x32x16_bf16(vf1, pa[kbv], o1, 0, 0, 0);
                __builtin_amdgcn_s_setprio(0);
            }
        }
    }

    float ls = lsv[0] + lsv[1] + lsv[2] + lsv[3];
    ls += __shfl_xor(ls, 32);
    float inv = 1.0f / ls;

    size_t crow = (size_t)b * 2048 + q0 + l31;
    unsigned short* cp = ctx + crow * 1024 + h * 64;
    #pragma unroll
    for (int r = 0; r < 16; ++r){
        int d = (r & 3) + 8 * (r >> 2) + 4 * hi;
        cp[d]      = f2bf(o0[r] * inv);
        cp[d + 32] = f2bf(o1[r] * inv);
    }
}

extern "C" void kernel_launch(void* const* d_in, const int* in_sizes, int n_in,
                              void* d_out, int out_size, void* d_ws, size_t ws_size,
                              hipStream_t stream) {
    const float* x      = (const float*)d_in[0];
    const float* w_qkv  = (const float*)d_in[1];
    const float* w_proj = (const float*)d_in[2];
    float* out = (float*)d_out;

    char* ws = (char*)d_ws;
    float*          cost   = (float*)(ws);                    // 65536 f32
    float*          sint   = (float*)(ws + 262144);           // 65536 f32
    unsigned short* xbf    = (unsigned short*)(ws + 524288);  // 8388608 bf16 (reused as ctx)
    unsigned short* qb     = (unsigned short*)(ws + 17301504);
    unsigned short* kb     = (unsigned short*)(ws + 34078720);
    unsigned short* vtb    = (unsigned short*)(ws + 50855936); // [bh][d][key]
    unsigned short* wqkvT  = (unsigned short*)(ws + 67633152); // [3072][1024]
    unsigned short* wprojT = (unsigned short*)(ws + 73924608); // [1024][1024]
    unsigned short* ctxbf  = xbf;                              // reuse after qkv GEMM

    rope_table_kernel<<<256, 256, 0, stream>>>(cost, sint);

    cvt_bf16_kernel<<<8192, 256, 0, stream>>>(x, xbf);

    dim3 gt1(48, 16);
    transpose_bf16_kernel<<<gt1, 256, 0, stream>>>(w_qkv, wqkvT, 1024, 3072);
    dim3 gt2(16, 16);
    transpose_bf16_kernel<<<gt2, 256, 0, stream>>>(w_proj, wprojT, 1024, 1024);

    dim3 g1(24, 64);
    qkv_mfma_kernel<<<g1, 512, 0, stream>>>(xbf, wqkvT, cost, sint, qb, kb, vtb);

    attn_mfma32_kernel<<<512, 512, 0, stream>>>(qb, kb, vtb, ctxbf);

    dim3 g3(8, 64);
    proj_mfma_kernel<<<g3, 256, 0, stream>>>(ctxbf, wprojT, out);
}

// Round 20
// 186.812 us; speedup vs baseline: 1.2217x; 1.2217x over previous
//
#include <hip/hip_runtime.h>

#define L_SEQ   2048
#define D_MODEL 1024
#define N_QKV   3072

typedef __attribute__((ext_vector_type(8)))  short short8;
typedef __attribute__((ext_vector_type(4)))  float f32x4;
typedef __attribute__((ext_vector_type(16))) float f32x16;

__device__ __forceinline__ unsigned short f2bf(float f){
    unsigned int u = __float_as_uint(f);
    u += 0x7fffu + ((u >> 16) & 1u);
    return (unsigned short)(u >> 16);
}

__device__ __forceinline__ void gload16(const void* g, void* l){
    __builtin_amdgcn_global_load_lds(
        (const __attribute__((address_space(1))) unsigned int*)g,
        (__attribute__((address_space(3))) unsigned int*)l, 16, 0, 0);
}

__device__ __forceinline__ unsigned int cvtpk_bf16(float lo, float hi){
    unsigned int r;
    asm volatile("v_cvt_pk_bf16_f32 %0, %1, %2" : "=v"(r) : "v"(lo), "v"(hi));
    return r;
}

// ---------------- RoPE cos/sin table ----------------
__global__ void rope_table_kernel(float* __restrict__ cost, float* __restrict__ sint){
    int idx = blockIdx.x * blockDim.x + threadIdx.x;   // l*32 + i
    if (idx >= L_SEQ * 32) return;
    int l = idx >> 5;
    int i = idx & 31;
    double e = (double)(2 * i) / 64.0;
    float invf = (float)pow(10000.0, -e);
    float f = (float)l * invf;
    cost[idx] = cosf(f);
    sint[idx] = sinf(f);
}

// ---------------- fp32 -> bf16 elementwise ----------------
__global__ __launch_bounds__(256) void cvt_bf16_kernel(
    const float* __restrict__ in, unsigned short* __restrict__ out)
{
    int i = (blockIdx.x * 256 + threadIdx.x) * 4;
    float4 v = *(const float4*)(in + i);
    ushort4 o;
    o.x = f2bf(v.x); o.y = f2bf(v.y); o.z = f2bf(v.z); o.w = f2bf(v.w);
    *(ushort4*)(out + i) = o;
}

// ---------------- transpose + convert: W[K][N] fp32 -> WT[N][K] bf16 ----------------
__global__ __launch_bounds__(256) void transpose_bf16_kernel(
    const float* __restrict__ W, unsigned short* __restrict__ WT, int K, int N)
{
    __shared__ float T[64][65];
    const int k0 = blockIdx.y * 64, n0 = blockIdx.x * 64;
    const int r  = threadIdx.x >> 4;
    const int c4 = (threadIdx.x & 15) * 4;
    #pragma unroll
    for (int i = 0; i < 4; ++i){
        int row = r + i * 16;
        float4 v = *(const float4*)&W[(size_t)(k0 + row) * N + n0 + c4];
        T[row][c4 + 0] = v.x; T[row][c4 + 1] = v.y;
        T[row][c4 + 2] = v.z; T[row][c4 + 3] = v.w;
    }
    __syncthreads();
    #pragma unroll
    for (int i = 0; i < 4; ++i){
        int nl = r + i * 16;
        ushort4 o;
        o.x = f2bf(T[c4 + 0][nl]); o.y = f2bf(T[c4 + 1][nl]);
        o.z = f2bf(T[c4 + 2][nl]); o.w = f2bf(T[c4 + 3][nl]);
        *(ushort4*)&WT[(size_t)(n0 + nl) * K + k0 + c4] = o;
    }
}

// ---------------- QKV MFMA GEMM (8192x3072x1024) + RoPE + LDS-staged stores ----------
// 512 threads / 8 waves per 128x128 tile; BK=64 single-buffer 2-barrier loop.
// q -> [bh][l][d] (scaled by exactly 0.125); k -> [bh][key][d]; v -> [bh][d][key]
__global__ __launch_bounds__(512, 4) void qkv_mfma_kernel(
    const unsigned short* __restrict__ A, const unsigned short* __restrict__ BT,
    const float* __restrict__ cost, const float* __restrict__ sint,
    unsigned short* __restrict__ qb, unsigned short* __restrict__ kb,
    unsigned short* __restrict__ vtb)
{
    __shared__ __align__(16) unsigned char smem[34816];   // Al(16K)+Bl(16K) / T 128x136
    unsigned short* Al = (unsigned short*)smem;
    unsigned short* Bl = Al + 8192;
    unsigned short* T  = (unsigned short*)smem;           // [128][136] after K-loop

    const int tid  = threadIdx.x;
    const int lane = tid & 63;
    const int w    = tid >> 6;          // 0..7
    const int wm   = w & 1, wn = w >> 1;   // m-half, n-quarter
    const int l15  = lane & 15, l4 = lane >> 4;
    const int m0   = blockIdx.y * 128;
    const int n0   = blockIdx.x * 128;

    const int srow = tid >> 3;          // 0..63
    const int scol = ((tid & 7) * 8) ^ ((srow & 7) * 8);   // T2 pre-swizzled source
    const int ksw  = (l15 & 7) * 8;                        // read-side XOR key

    f32x4 acc[4][2];
    #pragma unroll
    for (int i = 0; i < 4; ++i)
        #pragma unroll
        for (int j = 0; j < 2; ++j)
            acc[i][j] = (f32x4){0.f, 0.f, 0.f, 0.f};

    for (int k0 = 0; k0 < 1024; k0 += 64){
        #pragma unroll
        for (int c = 0; c < 2; ++c){
            gload16(&A [(size_t)(m0 + c * 64 + srow) * 1024 + k0 + scol],
                    &Al[c * 4096 + w * 512]);
            gload16(&BT[(size_t)(n0 + c * 64 + srow) * 1024 + k0 + scol],
                    &Bl[c * 4096 + w * 512]);
        }
        __syncthreads();
        #pragma unroll
        for (int kc = 0; kc < 2; ++kc){
            short8 a[4], b[2];
            #pragma unroll
            for (int mi = 0; mi < 4; ++mi)
                a[mi] = *(const short8*)&Al[(wm * 64 + mi * 16 + l15) * 64 + ((kc * 32 + l4 * 8) ^ ksw)];
            #pragma unroll
            for (int ni = 0; ni < 2; ++ni)
                b[ni] = *(const short8*)&Bl[(wn * 32 + ni * 16 + l15) * 64 + ((kc * 32 + l4 * 8) ^ ksw)];
            #pragma unroll
            for (int mi = 0; mi < 4; ++mi)
                #pragma unroll
                for (int ni = 0; ni < 2; ++ni)
                    acc[mi][ni] = __builtin_amdgcn_mfma_f32_16x16x32_bf16(a[mi], b[ni], acc[mi][ni], 0, 0, 0);
        }
        __syncthreads();
    }

    // ---- epilogue: RoPE in registers -> LDS tile -> coalesced 16B stores ----
    const int which = n0 >> 10;           // block-uniform: 0=q 1=k 2=v
    #pragma unroll
    for (int ni = 0; ni < 2; ++ni){
        const int c  = wn * 32 + ni * 16 + l15;       // block-local col
        const int d  = (n0 + c) & 63;
        const int fi = d >> 1;
        const float sgn = (d & 1) ? 1.0f : -1.0f;
        #pragma unroll
        for (int mi = 0; mi < 4; ++mi){
            const int row0 = wm * 64 + mi * 16 + l4 * 4;
            if (which == 2){
                ushort4 pk;
                pk.x = f2bf(acc[mi][ni][0]); pk.y = f2bf(acc[mi][ni][1]);
                pk.z = f2bf(acc[mi][ni][2]); pk.w = f2bf(acc[mi][ni][3]);
                *(ushort4*)&T[c * 136 + row0] = pk;            // transposed [c][l]
            } else {
                #pragma unroll
                for (int r = 0; r < 4; ++r){
                    int row = row0 + r;
                    int gl  = (m0 + row) & 2047;
                    float val = acc[mi][ni][r];
                    float cs = cost[gl * 32 + fi];
                    float sn = sint[gl * 32 + fi];
                    float partner = __shfl_xor(val, 1);
                    float outv = val * cs + sgn * partner * sn;
                    // q scaled by exactly 1/8 (bf16-exact); softmax runs base-e
                    if (which == 0) outv *= 0.125f;
                    T[row * 136 + c] = f2bf(outv);             // natural [l][c]
                }
            }
        }
    }
    __syncthreads();

    const int bidx = m0 >> 11;
    if (which == 2){
        #pragma unroll
        for (int it = 0; it < 4; ++it){
            int chunk = it * 512 + tid;       // 128 c-rows x 16 l-chunks
            int crow  = chunk >> 4;
            int lch   = chunk & 15;
            short8 v = *(const short8*)&T[crow * 136 + lch * 8];
            int colg = n0 + crow;
            int hh   = (colg & 1023) >> 6;
            int d    = colg & 63;
            int l0   = (m0 & 2047) + lch * 8;
            *(short8*)&vtb[(((size_t)(bidx * 16 + hh)) * 64 + d) * 2048 + l0] = v;
        }
    } else {
        unsigned short* dstb = (which == 0) ? qb : kb;
        #pragma unroll
        for (int it = 0; it < 4; ++it){
            int chunk = it * 512 + tid;       // 128 l-rows x 16 d-chunks
            int row   = chunk >> 4;
            int ch    = chunk & 15;
            short8 v = *(const short8*)&T[row * 136 + ch * 8];
            int gl   = (m0 & 2047) + row;
            int colg = n0 + ch * 8;
            int hh   = (colg & 1023) >> 6;
            int d0   = colg & 63;
            *(short8*)&dstb[(((size_t)(bidx * 16 + hh)) * 2048 + gl) * 64 + d0] = v;
        }
    }
}

// ---------------- proj MFMA GEMM (8192x1024x1024), fp32 out ----------------
__global__ __launch_bounds__(256, 3) void proj_mfma_kernel(
    const unsigned short* __restrict__ A, const unsigned short* __restrict__ BT,
    float* __restrict__ C)
{
    __shared__ __align__(16) unsigned short Al[128 * 64];
    __shared__ __align__(16) unsigned short Bl[128 * 64];

    const int tid  = threadIdx.x;
    const int lane = tid & 63;
    const int w    = tid >> 6;
    const int wm   = w & 1, wn = w >> 1;
    const int l15  = lane & 15, l4 = lane >> 4;
    const int m0   = blockIdx.y * 128;
    const int n0   = blockIdx.x * 128;

    const int srow = tid >> 3;
    const int scol = ((tid & 7) * 8) ^ ((srow & 7) * 8);
    const int ksw  = (l15 & 7) * 8;

    f32x4 acc[4][4];
    #pragma unroll
    for (int i = 0; i < 4; ++i)
        #pragma unroll
        for (int j = 0; j < 4; ++j)
            acc[i][j] = (f32x4){0.f, 0.f, 0.f, 0.f};

    for (int k0 = 0; k0 < 1024; k0 += 64){
        #pragma unroll
        for (int c = 0; c < 4; ++c){
            gload16(&A [(size_t)(m0 + c * 32 + srow) * 1024 + k0 + scol],
                    &Al[c * 2048 + w * 512]);
            gload16(&BT[(size_t)(n0 + c * 32 + srow) * 1024 + k0 + scol],
                    &Bl[c * 2048 + w * 512]);
        }
        __syncthreads();
        #pragma unroll
        for (int kc = 0; kc < 2; ++kc){
            short8 a[4], b[4];
            #pragma unroll
            for (int mi = 0; mi < 4; ++mi)
                a[mi] = *(const short8*)&Al[(wm * 64 + mi * 16 + l15) * 64 + ((kc * 32 + l4 * 8) ^ ksw)];
            #pragma unroll
            for (int ni = 0; ni < 4; ++ni)
                b[ni] = *(const short8*)&Bl[(wn * 64 + ni * 16 + l15) * 64 + ((kc * 32 + l4 * 8) ^ ksw)];
            #pragma unroll
            for (int mi = 0; mi < 4; ++mi)
                #pragma unroll
                for (int ni = 0; ni < 4; ++ni)
                    acc[mi][ni] = __builtin_amdgcn_mfma_f32_16x16x32_bf16(a[mi], b[ni], acc[mi][ni], 0, 0, 0);
        }
        __syncthreads();
    }

    #pragma unroll
    for (int mi = 0; mi < 4; ++mi)
        #pragma unroll
        for (int r = 0; r < 4; ++r){
            int row = m0 + wm * 64 + mi * 16 + l4 * 4 + r;
            #pragma unroll
            for (int ni = 0; ni < 4; ++ni){
                int colc = n0 + wn * 64 + ni * 16 + l15;
                C[(size_t)row * 1024 + colc] = acc[mi][ni][r];
            }
        }
}

// ---------------- swapped-operand 32x32 MFMA flash attention ----------------
// 8 waves x 32 q; 3-buffer LDS (KVBLK=64), 1 barrier/tile, counted vmcnt(2);
// fixed-offset base-e softmax via __expf; QK chains interleaved (2-way ILP).
__global__ __launch_bounds__(512, 4) void attn_mfma32_kernel(
    const unsigned short* __restrict__ qb,   // [bh][l][d] (pre-scaled by 1/8)
    const unsigned short* __restrict__ kb,   // [bh][key][d]
    const unsigned short* __restrict__ vtb,  // [bh][d][key]
    unsigned short* __restrict__ ctx)        // [b*2048+l][1024] bf16
{
    __shared__ __align__(16) unsigned char lds[49152];  // 3 x (K 8KB + Vt 8KB)

    const int tid  = threadIdx.x;
    const int lane = tid & 63;
    const int w    = tid >> 6;          // 0..7
    const int l31  = lane & 31;
    const int hi   = lane >> 5;
    const int blk = blockIdx.x;                 // 0..511
    const int swz = ((blk & 7) << 6) | (blk >> 3);
    const int bh  = swz >> 3;                   // 0..63
    const int qt  = swz & 7;                    // 0..7
    const int b   = bh >> 4, h = bh & 15;

    const unsigned short* Kg  = kb  + (size_t)bh * 2048 * 64;
    const unsigned short* VTg = vtb + (size_t)bh * 64 * 2048;
    const int q0 = qt * 256 + w * 32;
    const unsigned short* Qg = qb + ((size_t)bh * 2048 + q0) * 64;

    short8 qf[4];
    #pragma unroll
    for (int kbd = 0; kbd < 4; ++kbd)
        qf[kbd] = *(const short8*)(Qg + l31 * 64 + hi * 8 + kbd * 16);

    f32x16 o0, o1;
    f32x4  lsv = (f32x4){0.f, 0.f, 0.f, 0.f};
    #pragma unroll
    for (int r = 0; r < 16; ++r){ o0[r] = 0.f; o1[r] = 0.f; }

    const unsigned short* ksrc = Kg + ((size_t)((w >> 2) * 32 + l31)) * 64 + hi * 8 + (w & 3) * 16;
    const unsigned short* vsrc = VTg + ((size_t)((w >> 2) * 32 + l31)) * 2048 + hi * 8 + (w & 3) * 16;

    auto STAGE = [&](int t, int buf){
        unsigned char* base = lds + buf * 16384 + w * 1024;
        gload16(ksrc + (size_t)t * 4096, base);          // K: advance 64 keys
        gload16(vsrc + (size_t)t * 64, base + 8192);     // V: advance 64 key-cols
    };

    STAGE(0, 0);
    STAGE(1, 1);

    int bufc = 0;
    for (int t = 0; t < 32; ++t){
        if (t < 31){
            asm volatile("s_waitcnt vmcnt(2)" ::: "memory");
        } else {
            asm volatile("s_waitcnt vmcnt(0)" ::: "memory");
        }
        __builtin_amdgcn_s_barrier();
        if (t < 30) STAGE(t + 2, (bufc == 0) ? 2 : bufc - 1);

        unsigned char* Kl = lds + bufc * 16384;
        unsigned char* Vl = Kl + 8192;

        // ---- QK^T: both key-groups interleaved (independent accumulators) ----
        f32x16 s0, s1;
        #pragma unroll
        for (int r = 0; r < 16; ++r){ s0[r] = -16.0f; s1[r] = -16.0f; }
        __builtin_amdgcn_s_setprio(1);
        #pragma unroll
        for (int kbd = 0; kbd < 4; ++kbd){
            short8 kfA = *(const short8*)(Kl + (0 * 4 + kbd) * 1024 + lane * 16);
            short8 kfB = *(const short8*)(Kl + (1 * 4 + kbd) * 1024 + lane * 16);
            s0 = __builtin_amdgcn_mfma_f32_32x32x16_bf16(kfA, qf[kbd], s0, 0, 0, 0);
            s1 = __builtin_amdgcn_mfma_f32_32x32x16_bf16(kfB, qf[kbd], s1, 0, 0, 0);
        }
        __builtin_amdgcn_s_setprio(0);

        // ---- p = exp(s - 16) via __expf; denominator accumulate ----
        #pragma unroll
        for (int r = 0; r < 16; ++r){
            float p0 = __expf(s0[r]);
            float p1 = __expf(s1[r]);
            s0[r] = p0; s1[r] = p1;
            lsv[r & 3] += p0 + p1;
        }

        // ---- pack to bf16 fragments via cvt_pk + permlane32_swap ----
        short8 pa[4];
        #pragma unroll
        for (int half = 0; half < 2; ++half){
            unsigned int w01 = cvtpk_bf16(s0[half*8+0], s0[half*8+1]);
            unsigned int w23 = cvtpk_bf16(s0[half*8+2], s0[half*8+3]);
            unsigned int w45 = cvtpk_bf16(s0[half*8+4], s0[half*8+5]);
            unsigned int w67 = cvtpk_bf16(s0[half*8+6], s0[half*8+7]);
            asm volatile("v_permlane32_swap_b32 %0, %1" : "+v"(w01), "+v"(w45));
            asm volatile("v_permlane32_swap_b32 %0, %1" : "+v"(w23), "+v"(w67));
            short8 pp;
            pp[0] = (short)(w01 & 0xffffu); pp[1] = (short)(w01 >> 16);
            pp[2] = (short)(w23 & 0xffffu); pp[3] = (short)(w23 >> 16);
            pp[4] = (short)(w45 & 0xffffu); pp[5] = (short)(w45 >> 16);
            pp[6] = (short)(w67 & 0xffffu); pp[7] = (short)(w67 >> 16);
            pa[half] = pp;
        }
        #pragma unroll
        for (int half = 0; half < 2; ++half){
            unsigned int w01 = cvtpk_bf16(s1[half*8+0], s1[half*8+1]);
            unsigned int w23 = cvtpk_bf16(s1[half*8+2], s1[half*8+3]);
            unsigned int w45 = cvtpk_bf16(s1[half*8+4], s1[half*8+5]);
            unsigned int w67 = cvtpk_bf16(s1[half*8+6], s1[half*8+7]);
            asm volatile("v_permlane32_swap_b32 %0, %1" : "+v"(w01), "+v"(w45));
            asm volatile("v_permlane32_swap_b32 %0, %1" : "+v"(w23), "+v"(w67));
            short8 pp;
            pp[0] = (short)(w01 & 0xffffu); pp[1] = (short)(w01 >> 16);
            pp[2] = (short)(w23 & 0xffffu); pp[3] = (short)(w23 >> 16);
            pp[4] = (short)(w45 & 0xffffu); pp[5] = (short)(w45 >> 16);
            pp[6] = (short)(w67 & 0xffffu); pp[7] = (short)(w67 >> 16);
            pa[2 + half] = pp;
        }

        // ---- O^T += V^T . P (o0/o1 alternate: 2-way ILP) ----
        #pragma unroll
        for (int kbv = 0; kbv < 4; ++kbv){
            short8 vf0 = *(const short8*)(Vl + (0 * 4 + kbv) * 1024 + lane * 16);
            short8 vf1 = *(const short8*)(Vl + (1 * 4 + kbv) * 1024 + lane * 16);
            __builtin_amdgcn_s_setprio(1);
            o0 = __builtin_amdgcn_mfma_f32_32x32x16_bf16(vf0, pa[kbv], o0, 0, 0, 0);
            o1 = __builtin_amdgcn_mfma_f32_32x32x16_bf16(vf1, pa[kbv], o1, 0, 0, 0);
            __builtin_amdgcn_s_setprio(0);
        }

        bufc = (bufc == 2) ? 0 : bufc + 1;
    }

    float ls = lsv[0] + lsv[1] + lsv[2] + lsv[3];
    ls += __shfl_xor(ls, 32);
    float inv = 1.0f / ls;

    size_t crow = (size_t)b * 2048 + q0 + l31;
    unsigned short* cp = ctx + crow * 1024 + h * 64;
    #pragma unroll
    for (int r = 0; r < 16; ++r){
        int d = (r & 3) + 8 * (r >> 2) + 4 * hi;
        cp[d]      = f2bf(o0[r] * inv);
        cp[d + 32] = f2bf(o1[r] * inv);
    }
}

extern "C" void kernel_launch(void* const* d_in, const int* in_sizes, int n_in,
                              void* d_out, int out_size, void* d_ws, size_t ws_size,
                              hipStream_t stream) {
    const float* x      = (const float*)d_in[0];
    const float* w_qkv  = (const float*)d_in[1];
    const float* w_proj = (const float*)d_in[2];
    float* out = (float*)d_out;

    char* ws = (char*)d_ws;
    float*          cost   = (float*)(ws);                    // 65536 f32
    float*          sint   = (float*)(ws + 262144);           // 65536 f32
    unsigned short* xbf    = (unsigned short*)(ws + 524288);  // 8388608 bf16 (reused as ctx)
    unsigned short* qb     = (unsigned short*)(ws + 17301504);
    unsigned short* kb     = (unsigned short*)(ws + 34078720);
    unsigned short* vtb    = (unsigned short*)(ws + 50855936); // [bh][d][key]
    unsigned short* wqkvT  = (unsigned short*)(ws + 67633152); // [3072][1024]
    unsigned short* wprojT = (unsigned short*)(ws + 73924608); // [1024][1024]
    unsigned short* ctxbf  = xbf;                              // reuse after qkv GEMM

    rope_table_kernel<<<256, 256, 0, stream>>>(cost, sint);

    cvt_bf16_kernel<<<8192, 256, 0, stream>>>(x, xbf);

    dim3 gt1(48, 16);
    transpose_bf16_kernel<<<gt1, 256, 0, stream>>>(w_qkv, wqkvT, 1024, 3072);
    dim3 gt2(16, 16);
    transpose_bf16_kernel<<<gt2, 256, 0, stream>>>(w_proj, wprojT, 1024, 1024);

    dim3 g1(24, 64);
    qkv_mfma_kernel<<<g1, 512, 0, stream>>>(xbf, wqkvT, cost, sint, qb, kb, vtb);

    attn_mfma32_kernel<<<512, 512, 0, stream>>>(qb, kb, vtb, ctxbf);

    dim3 g3(8, 64);
    proj_mfma_kernel<<<g3, 256, 0, stream>>>(ctxbf, wprojT, out);
}

// Round 21
// 177.517 us; speedup vs baseline: 1.2856x; 1.0524x over previous
//
#include <hip/hip_runtime.h>

#define L_SEQ   2048
#define D_MODEL 1024
#define N_QKV   3072

typedef __attribute__((ext_vector_type(8)))  short short8;
typedef __attribute__((ext_vector_type(4)))  float f32x4;
typedef __attribute__((ext_vector_type(16))) float f32x16;

__device__ __forceinline__ unsigned short f2bf(float f){
    unsigned int u = __float_as_uint(f);
    u += 0x7fffu + ((u >> 16) & 1u);
    return (unsigned short)(u >> 16);
}

__device__ __forceinline__ void gload16(const void* g, void* l){
    __builtin_amdgcn_global_load_lds(
        (const __attribute__((address_space(1))) unsigned int*)g,
        (__attribute__((address_space(3))) unsigned int*)l, 16, 0, 0);
}

__device__ __forceinline__ unsigned int cvtpk_bf16(float lo, float hi){
    unsigned int r;
    asm volatile("v_cvt_pk_bf16_f32 %0, %1, %2" : "=v"(r) : "v"(lo), "v"(hi));
    return r;
}

// ---------------- fused prologue: cvt x -> bf16 | transpose w_qkv | transpose w_proj | RoPE table ----
// blockIdx ranges: [0,8192) cvt, [8192,8960) wqkvT, [8960,9216) wprojT, [9216,9472) table.
// All four jobs are independent; fusing removes 3 launch boundaries and runs them concurrently.
__device__ __forceinline__ void transpose_body(
    const float* __restrict__ W, unsigned short* __restrict__ WT,
    int K, int N, int n0, int k0, int tid, float (*T)[65])
{
    const int r  = tid >> 4;
    const int c4 = (tid & 15) * 4;
    #pragma unroll
    for (int i = 0; i < 4; ++i){
        int row = r + i * 16;
        float4 v = *(const float4*)&W[(size_t)(k0 + row) * N + n0 + c4];
        T[row][c4 + 0] = v.x; T[row][c4 + 1] = v.y;
        T[row][c4 + 2] = v.z; T[row][c4 + 3] = v.w;
    }
    __syncthreads();
    #pragma unroll
    for (int i = 0; i < 4; ++i){
        int nl = r + i * 16;
        ushort4 o;
        o.x = f2bf(T[c4 + 0][nl]); o.y = f2bf(T[c4 + 1][nl]);
        o.z = f2bf(T[c4 + 2][nl]); o.w = f2bf(T[c4 + 3][nl]);
        *(ushort4*)&WT[(size_t)(n0 + nl) * K + k0 + c4] = o;
    }
}

__global__ __launch_bounds__(256) void prologue_kernel(
    const float* __restrict__ x, const float* __restrict__ w_qkv,
    const float* __restrict__ w_proj,
    float* __restrict__ cost, float* __restrict__ sint,
    unsigned short* __restrict__ xbf, unsigned short* __restrict__ wqkvT,
    unsigned short* __restrict__ wprojT)
{
    __shared__ float T[64][65];
    const int bid = blockIdx.x;
    const int tid = threadIdx.x;

    if (bid < 8192){
        // fp32 -> bf16 elementwise (x)
        int i = (bid * 256 + tid) * 4;
        float4 v = *(const float4*)(x + i);
        ushort4 o;
        o.x = f2bf(v.x); o.y = f2bf(v.y); o.z = f2bf(v.z); o.w = f2bf(v.w);
        *(ushort4*)(xbf + i) = o;
    } else if (bid < 8960){
        // transpose+convert w_qkv [1024][3072] -> wqkvT [3072][1024]
        int t = bid - 8192;                 // 0..767 = 48 x 16
        int n0 = (t % 48) * 64, k0 = (t / 48) * 64;
        transpose_body(w_qkv, wqkvT, 1024, 3072, n0, k0, tid, T);
    } else if (bid < 9216){
        // transpose+convert w_proj [1024][1024] -> wprojT [1024][1024]
        int t = bid - 8960;                 // 0..255 = 16 x 16
        int n0 = (t % 16) * 64, k0 = (t / 16) * 64;
        transpose_body(w_proj, wprojT, 1024, 1024, n0, k0, tid, T);
    } else {
        // RoPE cos/sin table: idx = l*32 + i
        int idx = (bid - 9216) * 256 + tid;
        int l = idx >> 5;
        int i = idx & 31;
        double e = (double)(2 * i) / 64.0;
        float invf = (float)pow(10000.0, -e);
        float f = (float)l * invf;
        cost[idx] = cosf(f);
        sint[idx] = sinf(f);
    }
}

// ---------------- QKV MFMA GEMM (8192x3072x1024) + RoPE + LDS-staged stores ----------
// 512 threads / 8 waves per 128x128 tile; BK=64 single-buffer 2-barrier loop.
// q -> [bh][l][d] (scaled by exactly 0.125); k -> [bh][key][d]; v -> [bh][d][key]
__global__ __launch_bounds__(512, 4) void qkv_mfma_kernel(
    const unsigned short* __restrict__ A, const unsigned short* __restrict__ BT,
    const float* __restrict__ cost, const float* __restrict__ sint,
    unsigned short* __restrict__ qb, unsigned short* __restrict__ kb,
    unsigned short* __restrict__ vtb)
{
    __shared__ __align__(16) unsigned char smem[34816];   // Al(16K)+Bl(16K) / T 128x136
    unsigned short* Al = (unsigned short*)smem;
    unsigned short* Bl = Al + 8192;
    unsigned short* T  = (unsigned short*)smem;           // [128][136] after K-loop

    const int tid  = threadIdx.x;
    const int lane = tid & 63;
    const int w    = tid >> 6;          // 0..7
    const int wm   = w & 1, wn = w >> 1;   // m-half, n-quarter
    const int l15  = lane & 15, l4 = lane >> 4;
    const int m0   = blockIdx.y * 128;
    const int n0   = blockIdx.x * 128;

    const int srow = tid >> 3;          // 0..63
    const int scol = ((tid & 7) * 8) ^ ((srow & 7) * 8);   // T2 pre-swizzled source
    const int ksw  = (l15 & 7) * 8;                        // read-side XOR key

    f32x4 acc[4][2];
    #pragma unroll
    for (int i = 0; i < 4; ++i)
        #pragma unroll
        for (int j = 0; j < 2; ++j)
            acc[i][j] = (f32x4){0.f, 0.f, 0.f, 0.f};

    for (int k0 = 0; k0 < 1024; k0 += 64){
        #pragma unroll
        for (int c = 0; c < 2; ++c){
            gload16(&A [(size_t)(m0 + c * 64 + srow) * 1024 + k0 + scol],
                    &Al[c * 4096 + w * 512]);
            gload16(&BT[(size_t)(n0 + c * 64 + srow) * 1024 + k0 + scol],
                    &Bl[c * 4096 + w * 512]);
        }
        __syncthreads();
        #pragma unroll
        for (int kc = 0; kc < 2; ++kc){
            short8 a[4], b[2];
            #pragma unroll
            for (int mi = 0; mi < 4; ++mi)
                a[mi] = *(const short8*)&Al[(wm * 64 + mi * 16 + l15) * 64 + ((kc * 32 + l4 * 8) ^ ksw)];
            #pragma unroll
            for (int ni = 0; ni < 2; ++ni)
                b[ni] = *(const short8*)&Bl[(wn * 32 + ni * 16 + l15) * 64 + ((kc * 32 + l4 * 8) ^ ksw)];
            #pragma unroll
            for (int mi = 0; mi < 4; ++mi)
                #pragma unroll
                for (int ni = 0; ni < 2; ++ni)
                    acc[mi][ni] = __builtin_amdgcn_mfma_f32_16x16x32_bf16(a[mi], b[ni], acc[mi][ni], 0, 0, 0);
        }
        __syncthreads();
    }

    // ---- epilogue: RoPE in registers -> LDS tile -> coalesced 16B stores ----
    const int which = n0 >> 10;           // block-uniform: 0=q 1=k 2=v
    #pragma unroll
    for (int ni = 0; ni < 2; ++ni){
        const int c  = wn * 32 + ni * 16 + l15;       // block-local col
        const int d  = (n0 + c) & 63;
        const int fi = d >> 1;
        const float sgn = (d & 1) ? 1.0f : -1.0f;
        #pragma unroll
        for (int mi = 0; mi < 4; ++mi){
            const int row0 = wm * 64 + mi * 16 + l4 * 4;
            if (which == 2){
                ushort4 pk;
                pk.x = f2bf(acc[mi][ni][0]); pk.y = f2bf(acc[mi][ni][1]);
                pk.z = f2bf(acc[mi][ni][2]); pk.w = f2bf(acc[mi][ni][3]);
                *(ushort4*)&T[c * 136 + row0] = pk;            // transposed [c][l]
            } else {
                #pragma unroll
                for (int r = 0; r < 4; ++r){
                    int row = row0 + r;
                    int gl  = (m0 + row) & 2047;
                    float val = acc[mi][ni][r];
                    float cs = cost[gl * 32 + fi];
                    float sn = sint[gl * 32 + fi];
                    float partner = __shfl_xor(val, 1);
                    float outv = val * cs + sgn * partner * sn;
                    // q scaled by exactly 1/8 (bf16-exact); softmax runs base-e
                    if (which == 0) outv *= 0.125f;
                    T[row * 136 + c] = f2bf(outv);             // natural [l][c]
                }
            }
        }
    }
    __syncthreads();

    const int bidx = m0 >> 11;
    if (which == 2){
        #pragma unroll
        for (int it = 0; it < 4; ++it){
            int chunk = it * 512 + tid;       // 128 c-rows x 16 l-chunks
            int crow  = chunk >> 4;
            int lch   = chunk & 15;
            short8 v = *(const short8*)&T[crow * 136 + lch * 8];
            int colg = n0 + crow;
            int hh   = (colg & 1023) >> 6;
            int d    = colg & 63;
            int l0   = (m0 & 2047) + lch * 8;
            *(short8*)&vtb[(((size_t)(bidx * 16 + hh)) * 64 + d) * 2048 + l0] = v;
        }
    } else {
        unsigned short* dstb = (which == 0) ? qb : kb;
        #pragma unroll
        for (int it = 0; it < 4; ++it){
            int chunk = it * 512 + tid;       // 128 l-rows x 16 d-chunks
            int row   = chunk >> 4;
            int ch    = chunk & 15;
            short8 v = *(const short8*)&T[row * 136 + ch * 8];
            int gl   = (m0 & 2047) + row;
            int colg = n0 + ch * 8;
            int hh   = (colg & 1023) >> 6;
            int d0   = colg & 63;
            *(short8*)&dstb[(((size_t)(bidx * 16 + hh)) * 2048 + gl) * 64 + d0] = v;
        }
    }
}

// ---------------- proj MFMA GEMM (8192x1024x1024), fp32 out ----------------
__global__ __launch_bounds__(256, 3) void proj_mfma_kernel(
    const unsigned short* __restrict__ A, const unsigned short* __restrict__ BT,
    float* __restrict__ C)
{
    __shared__ __align__(16) unsigned short Al[128 * 64];
    __shared__ __align__(16) unsigned short Bl[128 * 64];

    const int tid  = threadIdx.x;
    const int lane = tid & 63;
    const int w    = tid >> 6;
    const int wm   = w & 1, wn = w >> 1;
    const int l15  = lane & 15, l4 = lane >> 4;
    const int m0   = blockIdx.y * 128;
    const int n0   = blockIdx.x * 128;

    const int srow = tid >> 3;
    const int scol = ((tid & 7) * 8) ^ ((srow & 7) * 8);
    const int ksw  = (l15 & 7) * 8;

    f32x4 acc[4][4];
    #pragma unroll
    for (int i = 0; i < 4; ++i)
        #pragma unroll
        for (int j = 0; j < 4; ++j)
            acc[i][j] = (f32x4){0.f, 0.f, 0.f, 0.f};

    for (int k0 = 0; k0 < 1024; k0 += 64){
        #pragma unroll
        for (int c = 0; c < 4; ++c){
            gload16(&A [(size_t)(m0 + c * 32 + srow) * 1024 + k0 + scol],
                    &Al[c * 2048 + w * 512]);
            gload16(&BT[(size_t)(n0 + c * 32 + srow) * 1024 + k0 + scol],
                    &Bl[c * 2048 + w * 512]);
        }
        __syncthreads();
        #pragma unroll
        for (int kc = 0; kc < 2; ++kc){
            short8 a[4], b[4];
            #pragma unroll
            for (int mi = 0; mi < 4; ++mi)
                a[mi] = *(const short8*)&Al[(wm * 64 + mi * 16 + l15) * 64 + ((kc * 32 + l4 * 8) ^ ksw)];
            #pragma unroll
            for (int ni = 0; ni < 4; ++ni)
                b[ni] = *(const short8*)&Bl[(wn * 64 + ni * 16 + l15) * 64 + ((kc * 32 + l4 * 8) ^ ksw)];
            #pragma unroll
            for (int mi = 0; mi < 4; ++mi)
                #pragma unroll
                for (int ni = 0; ni < 4; ++ni)
                    acc[mi][ni] = __builtin_amdgcn_mfma_f32_16x16x32_bf16(a[mi], b[ni], acc[mi][ni], 0, 0, 0);
        }
        __syncthreads();
    }

    #pragma unroll
    for (int mi = 0; mi < 4; ++mi)
        #pragma unroll
        for (int r = 0; r < 4; ++r){
            int row = m0 + wm * 64 + mi * 16 + l4 * 4 + r;
            #pragma unroll
            for (int ni = 0; ni < 4; ++ni){
                int colc = n0 + wn * 64 + ni * 16 + l15;
                C[(size_t)row * 1024 + colc] = acc[mi][ni][r];
            }
        }
}

// ---------------- swapped-operand 32x32 MFMA flash attention ----------------
// 8 waves x 32 q; 3-buffer LDS (KVBLK=64), 1 barrier/tile, counted vmcnt(2);
// fixed-offset base-e softmax via __expf; QK chains interleaved (2-way ILP).
__global__ __launch_bounds__(512, 4) void attn_mfma32_kernel(
    const unsigned short* __restrict__ qb,   // [bh][l][d] (pre-scaled by 1/8)
    const unsigned short* __restrict__ kb,   // [bh][key][d]
    const unsigned short* __restrict__ vtb,  // [bh][d][key]
    unsigned short* __restrict__ ctx)        // [b*2048+l][1024] bf16
{
    __shared__ __align__(16) unsigned char lds[49152];  // 3 x (K 8KB + Vt 8KB)

    const int tid  = threadIdx.x;
    const int lane = tid & 63;
    const int w    = tid >> 6;          // 0..7
    const int l31  = lane & 31;
    const int hi   = lane >> 5;
    const int blk = blockIdx.x;                 // 0..511
    const int swz = ((blk & 7) << 6) | (blk >> 3);
    const int bh  = swz >> 3;                   // 0..63
    const int qt  = swz & 7;                    // 0..7
    const int b   = bh >> 4, h = bh & 15;

    const unsigned short* Kg  = kb  + (size_t)bh * 2048 * 64;
    const unsigned short* VTg = vtb + (size_t)bh * 64 * 2048;
    const int q0 = qt * 256 + w * 32;
    const unsigned short* Qg = qb + ((size_t)bh * 2048 + q0) * 64;

    short8 qf[4];
    #pragma unroll
    for (int kbd = 0; kbd < 4; ++kbd)
        qf[kbd] = *(const short8*)(Qg + l31 * 64 + hi * 8 + kbd * 16);

    f32x16 o0, o1;
    f32x4  lsv = (f32x4){0.f, 0.f, 0.f, 0.f};
    #pragma unroll
    for (int r = 0; r < 16; ++r){ o0[r] = 0.f; o1[r] = 0.f; }

    const unsigned short* ksrc = Kg + ((size_t)((w >> 2) * 32 + l31)) * 64 + hi * 8 + (w & 3) * 16;
    const unsigned short* vsrc = VTg + ((size_t)((w >> 2) * 32 + l31)) * 2048 + hi * 8 + (w & 3) * 16;

    auto STAGE = [&](int t, int buf){
        unsigned char* base = lds + buf * 16384 + w * 1024;
        gload16(ksrc + (size_t)t * 4096, base);          // K: advance 64 keys
        gload16(vsrc + (size_t)t * 64, base + 8192);     // V: advance 64 key-cols
    };

    STAGE(0, 0);
    STAGE(1, 1);

    int bufc = 0;
    for (int t = 0; t < 32; ++t){
        if (t < 31){
            asm volatile("s_waitcnt vmcnt(2)" ::: "memory");
        } else {
            asm volatile("s_waitcnt vmcnt(0)" ::: "memory");
        }
        __builtin_amdgcn_s_barrier();
        if (t < 30) STAGE(t + 2, (bufc == 0) ? 2 : bufc - 1);

        unsigned char* Kl = lds + bufc * 16384;
        unsigned char* Vl = Kl + 8192;

        // ---- QK^T: both key-groups interleaved (independent accumulators) ----
        f32x16 s0, s1;
        #pragma unroll
        for (int r = 0; r < 16; ++r){ s0[r] = -16.0f; s1[r] = -16.0f; }
        __builtin_amdgcn_s_setprio(1);
        #pragma unroll
        for (int kbd = 0; kbd < 4; ++kbd){
            short8 kfA = *(const short8*)(Kl + (0 * 4 + kbd) * 1024 + lane * 16);
            short8 kfB = *(const short8*)(Kl + (1 * 4 + kbd) * 1024 + lane * 16);
            s0 = __builtin_amdgcn_mfma_f32_32x32x16_bf16(kfA, qf[kbd], s0, 0, 0, 0);
            s1 = __builtin_amdgcn_mfma_f32_32x32x16_bf16(kfB, qf[kbd], s1, 0, 0, 0);
        }
        __builtin_amdgcn_s_setprio(0);

        // ---- p = exp(s - 16) via __expf; denominator accumulate ----
        #pragma unroll
        for (int r = 0; r < 16; ++r){
            float p0 = __expf(s0[r]);
            float p1 = __expf(s1[r]);
            s0[r] = p0; s1[r] = p1;
            lsv[r & 3] += p0 + p1;
        }

        // ---- pack to bf16 fragments via cvt_pk + permlane32_swap ----
        short8 pa[4];
        #pragma unroll
        for (int half = 0; half < 2; ++half){
            unsigned int w01 = cvtpk_bf16(s0[half*8+0], s0[half*8+1]);
            unsigned int w23 = cvtpk_bf16(s0[half*8+2], s0[half*8+3]);
            unsigned int w45 = cvtpk_bf16(s0[half*8+4], s0[half*8+5]);
            unsigned int w67 = cvtpk_bf16(s0[half*8+6], s0[half*8+7]);
            asm volatile("v_permlane32_swap_b32 %0, %1" : "+v"(w01), "+v"(w45));
            asm volatile("v_permlane32_swap_b32 %0, %1" : "+v"(w23), "+v"(w67));
            short8 pp;
            pp[0] = (short)(w01 & 0xffffu); pp[1] = (short)(w01 >> 16);
            pp[2] = (short)(w23 & 0xffffu); pp[3] = (short)(w23 >> 16);
            pp[4] = (short)(w45 & 0xffffu); pp[5] = (short)(w45 >> 16);
            pp[6] = (short)(w67 & 0xffffu); pp[7] = (short)(w67 >> 16);
            pa[half] = pp;
        }
        #pragma unroll
        for (int half = 0; half < 2; ++half){
            unsigned int w01 = cvtpk_bf16(s1[half*8+0], s1[half*8+1]);
            unsigned int w23 = cvtpk_bf16(s1[half*8+2], s1[half*8+3]);
            unsigned int w45 = cvtpk_bf16(s1[half*8+4], s1[half*8+5]);
            unsigned int w67 = cvtpk_bf16(s1[half*8+6], s1[half*8+7]);
            asm volatile("v_permlane32_swap_b32 %0, %1" : "+v"(w01), "+v"(w45));
            asm volatile("v_permlane32_swap_b32 %0, %1" : "+v"(w23), "+v"(w67));
            short8 pp;
            pp[0] = (short)(w01 & 0xffffu); pp[1] = (short)(w01 >> 16);
            pp[2] = (short)(w23 & 0xffffu); pp[3] = (short)(w23 >> 16);
            pp[4] = (short)(w45 & 0xffffu); pp[5] = (short)(w45 >> 16);
            pp[6] = (short)(w67 & 0xffffu); pp[7] = (short)(w67 >> 16);
            pa[2 + half] = pp;
        }

        // ---- O^T += V^T . P (o0/o1 alternate: 2-way ILP) ----
        #pragma unroll
        for (int kbv = 0; kbv < 4; ++kbv){
            short8 vf0 = *(const short8*)(Vl + (0 * 4 + kbv) * 1024 + lane * 16);
            short8 vf1 = *(const short8*)(Vl + (1 * 4 + kbv) * 1024 + lane * 16);
            __builtin_amdgcn_s_setprio(1);
            o0 = __builtin_amdgcn_mfma_f32_32x32x16_bf16(vf0, pa[kbv], o0, 0, 0, 0);
            o1 = __builtin_amdgcn_mfma_f32_32x32x16_bf16(vf1, pa[kbv], o1, 0, 0, 0);
            __builtin_amdgcn_s_setprio(0);
        }

        bufc = (bufc == 2) ? 0 : bufc + 1;
    }

    float ls = lsv[0] + lsv[1] + lsv[2] + lsv[3];
    ls += __shfl_xor(ls, 32);
    float inv = 1.0f / ls;

    size_t crow = (size_t)b * 2048 + q0 + l31;
    unsigned short* cp = ctx + crow * 1024 + h * 64;
    #pragma unroll
    for (int r = 0; r < 16; ++r){
        int d = (r & 3) + 8 * (r >> 2) + 4 * hi;
        cp[d]      = f2bf(o0[r] * inv);
        cp[d + 32] = f2bf(o1[r] * inv);
    }
}

extern "C" void kernel_launch(void* const* d_in, const int* in_sizes, int n_in,
                              void* d_out, int out_size, void* d_ws, size_t ws_size,
                              hipStream_t stream) {
    const float* x      = (const float*)d_in[0];
    const float* w_qkv  = (const float*)d_in[1];
    const float* w_proj = (const float*)d_in[2];
    float* out = (float*)d_out;

    char* ws = (char*)d_ws;
    float*          cost   = (float*)(ws);                    // 65536 f32
    float*          sint   = (float*)(ws + 262144);           // 65536 f32
    unsigned short* xbf    = (unsigned short*)(ws + 524288);  // 8388608 bf16 (reused as ctx)
    unsigned short* qb     = (unsigned short*)(ws + 17301504);
    unsigned short* kb     = (unsigned short*)(ws + 34078720);
    unsigned short* vtb    = (unsigned short*)(ws + 50855936); // [bh][d][key]
    unsigned short* wqkvT  = (unsigned short*)(ws + 67633152); // [3072][1024]
    unsigned short* wprojT = (unsigned short*)(ws + 73924608); // [1024][1024]
    unsigned short* ctxbf  = xbf;                              // reuse after qkv GEMM

    // fused prologue: cvt(8192) | wqkvT(768) | wprojT(256) | table(256)
    prologue_kernel<<<9472, 256, 0, stream>>>(x, w_qkv, w_proj,
                                              cost, sint, xbf, wqkvT, wprojT);

    dim3 g1(24, 64);
    qkv_mfma_kernel<<<g1, 512, 0, stream>>>(xbf, wqkvT, cost, sint, qb, kb, vtb);

    attn_mfma32_kernel<<<512, 512, 0, stream>>>(qb, kb, vtb, ctxbf);

    dim3 g3(8, 64);
    proj_mfma_kernel<<<g3, 256, 0, stream>>>(ctxbf, wprojT, out);
}